// Round 9
// baseline (222.030 us; speedup 1.0000x reference)
//
#include <hip/hip_runtime.h>
#include <hip/hip_bf16.h>

#define NN 768
#define MD 1024
#define NPAIR 295296            // 768*769/2
#define NPBLK3 1154             // ceil(NPAIR/256)

typedef __attribute__((ext_vector_type(8))) short s16x8;
typedef __attribute__((ext_vector_type(4))) float f32x4;
typedef __attribute__((ext_vector_type(2))) float f32x2;
typedef __attribute__((ext_vector_type(2))) __bf16 b16x2;

__device__ __forceinline__ ushort bf16_rn(float f) {
    uint u = __builtin_bit_cast(uint, f);
    u += 0x7FFFu + ((u >> 16) & 1u);
    return (ushort)(u >> 16);
}

// inverse triangular index: p -> (i,j), off(i) = i*(1537-i)/2, j = i + p - off(i)
__device__ __forceinline__ void ptoij(int p, int& io, int& jo) {
    const float disc = (float)(1537 * 1537 - 8 * p);
    int i = (int)((1537.0f - sqrtf(disc)) * 0.5f);
    i = i < 0 ? 0 : (i > 767 ? 767 : i);
    while (i > 0 && p < i * (1537 - i) / 2) --i;
    while (i < 767 && p >= (i + 1) * (1536 - i) / 2) ++i;
    io = i;
    jo = i + (p - i * (1537 - i) / 2);
}

#define GLOAD16(gsrc, ldst)                                                        \
    __builtin_amdgcn_global_load_lds(                                              \
        (const __attribute__((address_space(1))) void*)(gsrc),                     \
        (__attribute__((address_space(3))) void*)(ldst), 16, 0, 0)

// ---------- one-time: W2 -> bf16 (RNE), chunk-major + XOR-swizzled -------------
// chunk c (m0=c*64): 128 rows(k) x 128B; byte-in-row = (mloc8*16) ^ ((k&7)<<4)
__global__ __launch_bounds__(256) void w2bf16(const float* __restrict__ W2,
                                              ushort* __restrict__ WhiS)
{
    const int id = blockIdx.x * 256 + threadIdx.x;
    const int k = id >> 7;
    const int m = (id & 127) * 8;
    const float4 a = *reinterpret_cast<const float4*>(W2 + k * MD + m);
    const float4 b = *reinterpret_cast<const float4*>(W2 + k * MD + m + 4);
    const float w[8] = {a.x, a.y, a.z, a.w, b.x, b.y, b.z, b.w};
    s16x8 h;
#pragma unroll
    for (int e = 0; e < 8; ++e) h[e] = (short)bf16_rn(w[e]);
    const int c = m >> 6;
    const int mloc8 = (m >> 3) & 7;
    const int byte = (mloc8 * 16) ^ ((k & 7) << 4);
    const int off = c * 8192 + ((k * 128 + byte) >> 1);
    *reinterpret_cast<s16x8*>(&WhiS[off]) = h;
}

// ---- macros (ambient locals; 8-wave block: each wave stages 2KB/chunk) --------
#define STAGE8(cc)                                                           \
    {                                                                        \
        const ushort* sh_ = WhiS + (cc) * 8192;                              \
        ushort* ld_ = Wh[(cc) & 3];                                          \
        _Pragma("unroll")                                                    \
        for (int q_ = 0; q_ < 2; ++q_) {                                     \
            const int off_ = (wv * 2 + q_) * 512;                            \
            GLOAD16(sh_ + off_ + lane * 8, ld_ + off_);                      \
        }                                                                    \
    }

// weights in sa/sc/sb pre-scaled by -log2(e): sigma = rcp(1 + 2^u)
// packed fp32 (v_pk_fma/v_pk_add) for fma+add; scalar trans
#define SIG_CHUNK(cc, dst)                                                   \
    {                                                                        \
        _Pragma("unroll")                                                    \
        for (int ks_ = 0; ks_ < 2; ++ks_) {                                  \
            const int m0_ = (cc) * 64 + ks_ * 32 + l4 * 8;                   \
            const f32x4 a0_ = *reinterpret_cast<const f32x4*>(&sa[m0_]);     \
            const f32x4 a1_ = *reinterpret_cast<const f32x4*>(&sa[m0_ + 4]); \
            const f32x4 c0_ = *reinterpret_cast<const f32x4*>(&sc[m0_]);     \
            const f32x4 c1_ = *reinterpret_cast<const f32x4*>(&sc[m0_ + 4]); \
            const f32x4 b0_ = *reinterpret_cast<const f32x4*>(&sb[m0_]);     \
            const f32x4 b1_ = *reinterpret_cast<const f32x4*>(&sb[m0_ + 4]); \
            _Pragma("unroll")                                                \
            for (int tm_ = 0; tm_ < 2; ++tm_) {                              \
                const f32x2 xi2_ = (f32x2){xia[tm_], xia[tm_]};              \
                const f32x2 xj2_ = (f32x2){xja[tm_], xja[tm_]};              \
                const f32x2 one2_ = (f32x2){1.f, 1.f};                       \
                union { s16x8 v; uint u[4]; } fr_;                           \
                _Pragma("unroll")                                            \
                for (int h_ = 0; h_ < 4; ++h_) {                             \
                    f32x2 av_, cv_, bv_;                                     \
                    if (h_ < 2) {                                            \
                        av_ = (f32x2){a0_[2 * h_], a0_[2 * h_ + 1]};         \
                        cv_ = (f32x2){c0_[2 * h_], c0_[2 * h_ + 1]};         \
                        bv_ = (f32x2){b0_[2 * h_], b0_[2 * h_ + 1]};         \
                    } else {                                                 \
                        av_ = (f32x2){a1_[2 * h_ - 4], a1_[2 * h_ - 3]};     \
                        cv_ = (f32x2){c1_[2 * h_ - 4], c1_[2 * h_ - 3]};     \
                        bv_ = (f32x2){b1_[2 * h_ - 4], b1_[2 * h_ - 3]};     \
                    }                                                        \
                    const f32x2 u2_ = __builtin_elementwise_fma(             \
                        xi2_, av_, __builtin_elementwise_fma(xj2_, cv_, bv_));\
                    f32x2 e2_;                                               \
                    e2_[0] = __builtin_amdgcn_exp2f(u2_[0]);                 \
                    e2_[1] = __builtin_amdgcn_exp2f(u2_[1]);                 \
                    const f32x2 t2_ = e2_ + one2_;                           \
                    b16x2 p_;                                                \
                    p_.x = (__bf16)__builtin_amdgcn_rcpf(t2_[0]);            \
                    p_.y = (__bf16)__builtin_amdgcn_rcpf(t2_[1]);            \
                    fr_.u[h_] = __builtin_bit_cast(uint, p_);                \
                }                                                            \
                dst[ks_][tm_] = fr_.v;                                       \
            }                                                                \
        }                                                                    \
    }

#define MFMA_STEP(cc, src)                                                   \
    {                                                                        \
        const ushort* wb_ = Wh[(cc) & 3];                                    \
        _Pragma("unroll")                                                    \
        for (int ks_ = 0; ks_ < 2; ++ks_) {                                  \
            _Pragma("unroll")                                                \
            for (int th_ = 0; th_ < 2; ++th_) {                              \
                s16x8 bh_[4];                                                \
                _Pragma("unroll")                                            \
                for (int tn_ = 0; tn_ < 4; ++tn_) {                          \
                    const int k_ = th_ * 64 + tn_ * 16 + l15;                \
                    const int byte_ = (ks_ * 64 + l4 * 16) ^ ((k_ & 7) << 4);\
                    const int idx_ = (k_ * 128 + byte_) >> 1;                \
                    bh_[tn_] = *reinterpret_cast<const s16x8*>(&wb_[idx_]);  \
                }                                                            \
                __builtin_amdgcn_s_setprio(1);                               \
                _Pragma("unroll")                                            \
                for (int tm_ = 0; tm_ < 2; ++tm_)                            \
                    _Pragma("unroll")                                        \
                    for (int tn_ = 0; tn_ < 4; ++tn_)                        \
                        acc[tm_][th_][tn_] = __builtin_amdgcn_mfma_f32_16x16x32_bf16( \
                            src[ks_][tm_], bh_[tn_], acc[tm_][th_][tn_], 0, 0, 0);    \
                __builtin_amdgcn_s_setprio(0);                               \
            }                                                                \
        }                                                                    \
    }

// ---------- main: 8 waves x 32 pairs, 4-deep Wh, barrier per 2 chunks ----------
__global__ __launch_bounds__(512, 4) void mlp_pairs(
    const float* __restrict__ x,
    const float* __restrict__ W1, const float* __restrict__ b1,
    const ushort* __restrict__ WhiS,
    const float* __restrict__ b2, const float* __restrict__ W3,
    const float* __restrict__ b3, float* __restrict__ K)
{
    __shared__ __align__(16) float sa[MD], sc[MD], sb[MD];
    __shared__ __align__(16) ushort Wh[4][8192];

    const int t = threadIdx.x;
    const int lane = t & 63, wv = t >> 6;
    const int l15 = lane & 15, l4 = lane >> 4;

    const float NL2E = -1.4426950408889634f;
    for (int m = t; m < MD; m += 512) {
        const float2 w = reinterpret_cast<const float2*>(W1)[m];
        sa[m] = w.x * NL2E;
        sc[m] = w.y * NL2E;
        sb[m] = b1[m] * NL2E;
    }

    const int pairbase = blockIdx.x * 256 + wv * 32;

    float xia[2], xja[2];
#pragma unroll
    for (int tm = 0; tm < 2; ++tm) {
        const int p = pairbase + tm * 16 + l15;
        if (p < NPAIR) {
            int i, j;
            ptoij(p, i, j);
            xia[tm] = x[i];
            xja[tm] = x[j];
        } else {
            xia[tm] = 0.f;
            xja[tm] = 0.f;
        }
    }

    f32x4 acc[2][2][4];
#pragma unroll
    for (int a = 0; a < 2; ++a)
#pragma unroll
        for (int th = 0; th < 2; ++th)
#pragma unroll
            for (int b = 0; b < 4; ++b) acc[a][th][b] = (f32x4){0.f, 0.f, 0.f, 0.f};

    STAGE8(0);
    STAGE8(1);
    __syncthreads();                 // sa/sc/sb written AND Wh[0],Wh[1] staged

    s16x8 ah[2][2];
    for (int c = 0; c < 16; c += 2) {
        if (c < 14) {
            STAGE8(c + 2);           // async into buffers (c+2)&3, (c+3)&3
            STAGE8(c + 3);
        }
        SIG_CHUNK(c, ah);
        MFMA_STEP(c, ah);
        SIG_CHUNK(c + 1, ah);
        MFMA_STEP(c + 1, ah);
        __syncthreads();             // staged bufs ready; reads of c,c+1 done
    }

    // epilogue: v = sum_k W3[k]*relu(h2 + b2[k]) + b3; reduce over 16 lanes (k)
    float w3v[2][4], b2v[2][4];
#pragma unroll
    for (int th = 0; th < 2; ++th)
#pragma unroll
        for (int tn = 0; tn < 4; ++tn) {
            const int k = th * 64 + tn * 16 + l15;
            w3v[th][tn] = W3[k];
            b2v[th][tn] = b2[k];
        }
    const float b3v = b3[0];
#pragma unroll
    for (int tm = 0; tm < 2; ++tm)
#pragma unroll
        for (int r = 0; r < 4; ++r) {
            float v = 0.f;
#pragma unroll
            for (int th = 0; th < 2; ++th)
#pragma unroll
                for (int tn = 0; tn < 4; ++tn)
                    v = fmaf(w3v[th][tn], fmaxf(acc[tm][th][tn][r] + b2v[th][tn], 0.f), v);
            v += __shfl_xor(v, 1, 16);
            v += __shfl_xor(v, 2, 16);
            v += __shfl_xor(v, 4, 16);
            v += __shfl_xor(v, 8, 16);
            if (l15 == 0) {
                const int p = pairbase + tm * 16 + l4 * 4 + r;
                if (p < NPAIR) {
                    int i, j;
                    ptoij(p, i, j);
                    K[i * NN + j] = v + b3v;
                }
            }
        }
}

// ---------- fallback fp32 MLP kernel (only if ws too small; never expected) ----
#define MC 32
#define JT 128
#define SPAD 132
__global__ __launch_bounds__(256) void mlp_fill(
    const float* __restrict__ x,
    const float* __restrict__ W1, const float* __restrict__ b1,
    const float* __restrict__ W2, const float* __restrict__ b2,
    const float* __restrict__ W3, const float* __restrict__ b3,
    float* __restrict__ K)
{
    const int i  = blockIdx.y;
    const int j0 = blockIdx.x * JT;
    if (j0 + JT - 1 < i) return;
    __shared__ float sA[MD];
    __shared__ float sCw[MD];
    __shared__ float sxj[JT];
    __shared__ float S[MC][SPAD];
    __shared__ float W2t[MC][SPAD];
    const int t = threadIdx.x;
    const float xi = x[i];
    for (int m = t; m < MD; m += 256) {
        const float2 w = reinterpret_cast<const float2*>(W1)[m];
        sA[m]  = fmaf(xi, w.x, b1[m]);
        sCw[m] = w.y;
    }
    if (t < JT) sxj[t] = x[j0 + t];
    const int tk = t & 15;
    const int tj = t >> 4;
    float w3r[8], b2r[8];
#pragma unroll
    for (int kk = 0; kk < 8; kk++) {
        w3r[kk] = W3[tk * 8 + kk];
        b2r[kk] = b2[tk * 8 + kk];
    }
    float acc[8][8];
#pragma unroll
    for (int jj = 0; jj < 8; jj++)
#pragma unroll
        for (int kk = 0; kk < 8; kk++) acc[jj][kk] = 0.f;
    const int jx   = t & 127;
    const int mseg = (t >> 7) * 16;
    __syncthreads();
    const float xjv = sxj[jx];
    for (int m0 = 0; m0 < MD; m0 += MC) {
#pragma unroll
        for (int q = 0; q < 4; q++) {
            const int f   = t + q * 256;
            const int k   = f >> 3;
            const int mm4 = (f & 7) * 4;
            const float4 w = *reinterpret_cast<const float4*>(W2 + k * MD + m0 + mm4);
            W2t[mm4 + 0][k] = w.x;
            W2t[mm4 + 1][k] = w.y;
            W2t[mm4 + 2][k] = w.z;
            W2t[mm4 + 3][k] = w.w;
        }
#pragma unroll
        for (int q = 0; q < 16; q++) {
            const int ml = mseg + q;
            const float z = fmaf(xjv, sCw[m0 + ml], sA[m0 + ml]);
            S[ml][jx] = 1.0f / (1.0f + __expf(-z));
        }
        __syncthreads();
#pragma unroll 4
        for (int mm = 0; mm < MC; mm++) {
            const float4 s0 = *reinterpret_cast<const float4*>(&S[mm][tj * 8]);
            const float4 s1 = *reinterpret_cast<const float4*>(&S[mm][tj * 8 + 4]);
            const float4 w0 = *reinterpret_cast<const float4*>(&W2t[mm][tk * 8]);
            const float4 w1 = *reinterpret_cast<const float4*>(&W2t[mm][tk * 8 + 4]);
            const float sj[8] = {s0.x, s0.y, s0.z, s0.w, s1.x, s1.y, s1.z, s1.w};
            const float wk[8] = {w0.x, w0.y, w0.z, w0.w, w1.x, w1.y, w1.z, w1.w};
#pragma unroll
            for (int jj = 0; jj < 8; jj++)
#pragma unroll
                for (int kk = 0; kk < 8; kk++)
                    acc[jj][kk] = fmaf(sj[jj], wk[kk], acc[jj][kk]);
        }
        __syncthreads();
    }
    const float b3v = b3[0];
#pragma unroll
    for (int jj = 0; jj < 8; jj++) {
        float v = 0.f;
#pragma unroll
        for (int kk = 0; kk < 8; kk++) {
            const float h = acc[jj][kk] + b2r[kk];
            v = fmaf(w3r[kk], fmaxf(h, 0.f), v);
        }
#pragma unroll
        for (int off = 8; off >= 1; off >>= 1)
            v += __shfl_xor(v, off, 16);
        if (tk == 0) {
            const int j = j0 + tj * 8 + jj;
            if (j >= i) K[i * NN + j] = v + b3v;
        }
    }
}

// ---------------- Kernel 2: C = K^T K (768^3 fp32 GEMM) --------------------
__global__ __launch_bounds__(256) void ktk(const float* __restrict__ K,
                                           float* __restrict__ C)
{
    const int b0 = blockIdx.x * 64;
    const int a0 = blockIdx.y * 64;
    __shared__ float Ka[64][68];
    __shared__ float Kb[64][68];
    const int t  = threadIdx.x;
    const int tb = t & 15;
    const int ta = t >> 4;
    float acc[4][4];
#pragma unroll
    for (int u = 0; u < 4; u++)
#pragma unroll
        for (int v = 0; v < 4; v++) acc[u][v] = 0.f;
    const int kmax = (a0 < b0 ? a0 : b0) + 64;
    for (int k0 = 0; k0 < kmax; k0 += 64) {
#pragma unroll
        for (int q = 0; q < 4; q++) {
            const int f  = t + q * 256;
            const int kk = f >> 4;
            const int c4 = (f & 15) * 4;
            *reinterpret_cast<float4*>(&Ka[kk][c4]) =
                *reinterpret_cast<const float4*>(K + (k0 + kk) * NN + a0 + c4);
            *reinterpret_cast<float4*>(&Kb[kk][c4]) =
                *reinterpret_cast<const float4*>(K + (k0 + kk) * NN + b0 + c4);
        }
        __syncthreads();
#pragma unroll 8
        for (int kk = 0; kk < 64; kk++) {
            const float4 av = *reinterpret_cast<const float4*>(&Ka[kk][ta * 4]);
            const float4 bv = *reinterpret_cast<const float4*>(&Kb[kk][tb * 4]);
            const float a4[4] = {av.x, av.y, av.z, av.w};
            const float b4[4] = {bv.x, bv.y, bv.z, bv.w};
#pragma unroll
            for (int u = 0; u < 4; u++)
#pragma unroll
                for (int v = 0; v < 4; v++)
                    acc[u][v] = fmaf(a4[u], b4[v], acc[u][v]);
        }
        __syncthreads();
    }
#pragma unroll
    for (int u = 0; u < 4; u++) {
        float4 o;
        o.x = acc[u][0]; o.y = acc[u][1]; o.z = acc[u][2]; o.w = acc[u][3];
        *reinterpret_cast<float4*>(C + (a0 + ta * 4 + u) * NN + b0 + tb * 4) = o;
    }
}

extern "C" void kernel_launch(void* const* d_in, const int* in_sizes, int n_in,
                              void* d_out, int out_size, void* d_ws, size_t ws_size,
                              hipStream_t stream)
{
    const float* x  = (const float*)d_in[0];
    const float* W1 = (const float*)d_in[1];
    const float* b1 = (const float*)d_in[2];
    const float* W2 = (const float*)d_in[3];
    const float* b2 = (const float*)d_in[4];
    const float* W3 = (const float*)d_in[5];
    const float* b3 = (const float*)d_in[6];
    float* Kmat = (float*)d_ws;                       // 2,359,296 B
    float* C    = (float*)d_out;

    const size_t kBytes = (size_t)NN * NN * sizeof(float);
    const size_t need   = kBytes + 262144;            // + W2 bf16 swizzled

    hipMemsetAsync(Kmat, 0, kBytes, stream);
    if (ws_size >= need) {
        ushort* WhiS = (ushort*)((char*)d_ws + kBytes);
        w2bf16<<<64, 256, 0, stream>>>(W2, WhiS);
        mlp_pairs<<<NPBLK3, 512, 0, stream>>>(x, W1, b1, WhiS, b2, W3, b3, Kmat);
    } else {
        mlp_fill<<<dim3(6, NN), 256, 0, stream>>>(x, W1, b1, W2, b2, W3, b3, Kmat);
    }
    ktk<<<dim3(NN / 64, NN / 64), 256, 0, stream>>>(Kmat, C);
}

// Round 10
// 179.426 us; speedup vs baseline: 1.2374x; 1.2374x over previous
//
#include <hip/hip_runtime.h>
#include <hip/hip_bf16.h>

#define NN 768
#define MD 1024
#define NPAIR 295296            // 768*769/2
#define NPBLK2 2307             // NPAIR / 128 (exact)

typedef __attribute__((ext_vector_type(8))) short s16x8;
typedef __attribute__((ext_vector_type(4))) float f32x4;
typedef __attribute__((ext_vector_type(2))) float f32x2;
typedef __attribute__((ext_vector_type(2))) __bf16 b16x2;

__device__ __forceinline__ ushort bf16_rn(float f) {
    uint u = __builtin_bit_cast(uint, f);
    u += 0x7FFFu + ((u >> 16) & 1u);
    return (ushort)(u >> 16);
}

// inverse triangular index: p -> (i,j), off(i) = i*(1537-i)/2, j = i + p - off(i)
__device__ __forceinline__ void ptoij(int p, int& io, int& jo) {
    const float disc = (float)(1537 * 1537 - 8 * p);
    int i = (int)((1537.0f - sqrtf(disc)) * 0.5f);
    i = i < 0 ? 0 : (i > 767 ? 767 : i);
    while (i > 0 && p < i * (1537 - i) / 2) --i;
    while (i < 767 && p >= (i + 1) * (1536 - i) / 2) ++i;
    io = i;
    jo = i + (p - i * (1537 - i) / 2);
}

#define GLOAD16(gsrc, ldst)                                                        \
    __builtin_amdgcn_global_load_lds(                                              \
        (const __attribute__((address_space(1))) void*)(gsrc),                     \
        (__attribute__((address_space(3))) void*)(ldst), 16, 0, 0)

// ---------- one-time: W2 -> bf16 (RNE), chunk-major + XOR-swizzled -------------
// chunk c (m0=c*64): 128 rows(k) x 128B; byte-in-row = (mloc8*16) ^ ((k&7)<<4)
__global__ __launch_bounds__(256) void w2bf16(const float* __restrict__ W2,
                                              ushort* __restrict__ WhiS)
{
    const int id = blockIdx.x * 256 + threadIdx.x;
    const int k = id >> 7;
    const int m = (id & 127) * 8;
    const float4 a = *reinterpret_cast<const float4*>(W2 + k * MD + m);
    const float4 b = *reinterpret_cast<const float4*>(W2 + k * MD + m + 4);
    const float w[8] = {a.x, a.y, a.z, a.w, b.x, b.y, b.z, b.w};
    s16x8 h;
#pragma unroll
    for (int e = 0; e < 8; ++e) h[e] = (short)bf16_rn(w[e]);
    const int c = m >> 6;
    const int mloc8 = (m >> 3) & 7;
    const int byte = (mloc8 * 16) ^ ((k & 7) << 4);
    const int off = c * 8192 + ((k * 128 + byte) >> 1);
    *reinterpret_cast<s16x8*>(&WhiS[off]) = h;
}

// ---- macros (ambient locals) ---------------------------------------------------
#define STAGE(cc)                                                            \
    {                                                                        \
        const ushort* sh_ = WhiS + (cc) * 8192;                              \
        ushort* ld_ = Wh[(cc) & 1];                                          \
        _Pragma("unroll")                                                    \
        for (int q_ = 0; q_ < 4; ++q_) {                                     \
            const int off_ = (wv * 4 + q_) * 512;                            \
            GLOAD16(sh_ + off_ + lane * 8, ld_ + off_);                      \
        }                                                                    \
    }

// weights in sa/sc/sb pre-scaled by -log2(e): sigma = rcp(1 + 2^u)
#define SIG_CHUNK(cc, dst)                                                   \
    {                                                                        \
        _Pragma("unroll")                                                    \
        for (int ks_ = 0; ks_ < 2; ++ks_) {                                  \
            const int m0_ = (cc) * 64 + ks_ * 32 + l4 * 8;                   \
            const f32x4 a0_ = *reinterpret_cast<const f32x4*>(&sa[m0_]);     \
            const f32x4 a1_ = *reinterpret_cast<const f32x4*>(&sa[m0_ + 4]); \
            const f32x4 c0_ = *reinterpret_cast<const f32x4*>(&sc[m0_]);     \
            const f32x4 c1_ = *reinterpret_cast<const f32x4*>(&sc[m0_ + 4]); \
            const f32x4 b0_ = *reinterpret_cast<const f32x4*>(&sb[m0_]);     \
            const f32x4 b1_ = *reinterpret_cast<const f32x4*>(&sb[m0_ + 4]); \
            _Pragma("unroll")                                                \
            for (int tm_ = 0; tm_ < 2; ++tm_) {                              \
                const f32x2 xi2_ = (f32x2){xia[tm_], xia[tm_]};              \
                const f32x2 xj2_ = (f32x2){xja[tm_], xja[tm_]};              \
                const f32x2 one2_ = (f32x2){1.f, 1.f};                       \
                union { s16x8 v; uint u[4]; } fr_;                           \
                _Pragma("unroll")                                            \
                for (int h_ = 0; h_ < 4; ++h_) {                             \
                    f32x2 av_, cv_, bv_;                                     \
                    if (h_ < 2) {                                            \
                        av_ = (f32x2){a0_[2 * h_], a0_[2 * h_ + 1]};         \
                        cv_ = (f32x2){c0_[2 * h_], c0_[2 * h_ + 1]};         \
                        bv_ = (f32x2){b0_[2 * h_], b0_[2 * h_ + 1]};         \
                    } else {                                                 \
                        av_ = (f32x2){a1_[2 * h_ - 4], a1_[2 * h_ - 3]};     \
                        cv_ = (f32x2){c1_[2 * h_ - 4], c1_[2 * h_ - 3]};     \
                        bv_ = (f32x2){b1_[2 * h_ - 4], b1_[2 * h_ - 3]};     \
                    }                                                        \
                    const f32x2 u2_ = __builtin_elementwise_fma(             \
                        xi2_, av_, __builtin_elementwise_fma(xj2_, cv_, bv_));\
                    f32x2 e2_;                                               \
                    e2_[0] = __builtin_amdgcn_exp2f(u2_[0]);                 \
                    e2_[1] = __builtin_amdgcn_exp2f(u2_[1]);                 \
                    const f32x2 t2_ = e2_ + one2_;                           \
                    b16x2 p_;                                                \
                    p_.x = (__bf16)__builtin_amdgcn_rcpf(t2_[0]);            \
                    p_.y = (__bf16)__builtin_amdgcn_rcpf(t2_[1]);            \
                    fr_.u[h_] = __builtin_bit_cast(uint, p_);                \
                }                                                            \
                dst[ks_][tm_] = fr_.v;                                       \
            }                                                                \
        }                                                                    \
    }

#define MFMA_STEP(cc, src)                                                   \
    {                                                                        \
        const ushort* wb_ = Wh[(cc) & 1];                                    \
        _Pragma("unroll")                                                    \
        for (int ks_ = 0; ks_ < 2; ++ks_) {                                  \
            _Pragma("unroll")                                                \
            for (int th_ = 0; th_ < 2; ++th_) {                              \
                s16x8 bh_[4];                                                \
                _Pragma("unroll")                                            \
                for (int tn_ = 0; tn_ < 4; ++tn_) {                          \
                    const int k_ = th_ * 64 + tn_ * 16 + l15;                \
                    const int byte_ = (ks_ * 64 + l4 * 16) ^ ((k_ & 7) << 4);\
                    const int idx_ = (k_ * 128 + byte_) >> 1;                \
                    bh_[tn_] = *reinterpret_cast<const s16x8*>(&wb_[idx_]);  \
                }                                                            \
                __builtin_amdgcn_s_setprio(1);                               \
                _Pragma("unroll")                                            \
                for (int tm_ = 0; tm_ < 2; ++tm_)                            \
                    _Pragma("unroll")                                        \
                    for (int tn_ = 0; tn_ < 4; ++tn_)                        \
                        acc[tm_][th_][tn_] = __builtin_amdgcn_mfma_f32_16x16x32_bf16( \
                            src[ks_][tm_], bh_[tn_], acc[tm_][th_][tn_], 0, 0, 0);    \
                __builtin_amdgcn_s_setprio(0);                               \
            }                                                                \
        }                                                                    \
    }

// ---------- main: 32 pairs/wave, 3 waves/SIMD, SIG(c+1) || MFMA(c) pipeline ----
__global__ __launch_bounds__(256, 3) void mlp_pairs(
    const float* __restrict__ x,
    const float* __restrict__ W1, const float* __restrict__ b1,
    const ushort* __restrict__ WhiS,
    const float* __restrict__ b2, const float* __restrict__ W3,
    const float* __restrict__ b3, float* __restrict__ K)
{
    __shared__ __align__(16) float sa[MD], sc[MD], sb[MD];
    __shared__ __align__(16) ushort Wh[2][8192];

    const int t = threadIdx.x;
    const int lane = t & 63, wv = t >> 6;
    const int l15 = lane & 15, l4 = lane >> 4;

    const float NL2E = -1.4426950408889634f;
    for (int m = t; m < MD; m += 256) {
        const float2 w = reinterpret_cast<const float2*>(W1)[m];
        sa[m] = w.x * NL2E;
        sc[m] = w.y * NL2E;
        sb[m] = b1[m] * NL2E;
    }

    const int pairbase = blockIdx.x * 128 + wv * 32;

    float xia[2], xja[2];
#pragma unroll
    for (int tm = 0; tm < 2; ++tm) {
        const int p = pairbase + tm * 16 + l15;
        if (p < NPAIR) {
            int i, j;
            ptoij(p, i, j);
            xia[tm] = x[i];
            xja[tm] = x[j];
        } else {
            xia[tm] = 0.f;
            xja[tm] = 0.f;
        }
    }

    f32x4 acc[2][2][4];
#pragma unroll
    for (int a = 0; a < 2; ++a)
#pragma unroll
        for (int th = 0; th < 2; ++th)
#pragma unroll
            for (int b = 0; b < 4; ++b) acc[a][th][b] = (f32x4){0.f, 0.f, 0.f, 0.f};

    STAGE(0);
    __syncthreads();                 // sa/sc/sb written AND Wh[0] staged

    s16x8 ahE[2][2], ahO[2][2];
    SIG_CHUNK(0, ahE);               // chunk 0 fragments ready before loop

    for (int cc = 0; cc < 8; ++cc) {
        const int c0 = cc * 2, c1 = cc * 2 + 1;
        STAGE(c1);                   // async into other buffer
        SIG_CHUNK(c1, ahO);          // independent of MFMA(c0) -> interleaves
        MFMA_STEP(c0, ahE);
        __syncthreads();             // Wh[c1] ready; reads of Wh[c0] done
        if (cc < 7) {
            STAGE(c1 + 1);
            SIG_CHUNK(c1 + 1, ahE);
        }
        MFMA_STEP(c1, ahO);
        __syncthreads();             // Wh[c1+1] ready; reads of Wh[c1] done
    }

    // epilogue: v = sum_k W3[k]*relu(h2 + b2[k]) + b3; reduce over 16 lanes (k)
    float w3v[2][4], b2v[2][4];
#pragma unroll
    for (int th = 0; th < 2; ++th)
#pragma unroll
        for (int tn = 0; tn < 4; ++tn) {
            const int k = th * 64 + tn * 16 + l15;
            w3v[th][tn] = W3[k];
            b2v[th][tn] = b2[k];
        }
    const float b3v = b3[0];
#pragma unroll
    for (int tm = 0; tm < 2; ++tm)
#pragma unroll
        for (int r = 0; r < 4; ++r) {
            float v = 0.f;
#pragma unroll
            for (int th = 0; th < 2; ++th)
#pragma unroll
                for (int tn = 0; tn < 4; ++tn)
                    v = fmaf(w3v[th][tn], fmaxf(acc[tm][th][tn][r] + b2v[th][tn], 0.f), v);
            v += __shfl_xor(v, 1, 16);
            v += __shfl_xor(v, 2, 16);
            v += __shfl_xor(v, 4, 16);
            v += __shfl_xor(v, 8, 16);
            if (l15 == 0) {
                const int p = pairbase + tm * 16 + l4 * 4 + r;
                if (p < NPAIR) {
                    int i, j;
                    ptoij(p, i, j);
                    K[i * NN + j] = v + b3v;
                }
            }
        }
}

// ---------- fallback fp32 MLP kernel (only if ws too small; never expected) ----
#define MC 32
#define JT 128
#define SPAD 132
__global__ __launch_bounds__(256) void mlp_fill(
    const float* __restrict__ x,
    const float* __restrict__ W1, const float* __restrict__ b1,
    const float* __restrict__ W2, const float* __restrict__ b2,
    const float* __restrict__ W3, const float* __restrict__ b3,
    float* __restrict__ K)
{
    const int i  = blockIdx.y;
    const int j0 = blockIdx.x * JT;
    if (j0 + JT - 1 < i) return;
    __shared__ float sA[MD];
    __shared__ float sCw[MD];
    __shared__ float sxj[JT];
    __shared__ float S[MC][SPAD];
    __shared__ float W2t[MC][SPAD];
    const int t = threadIdx.x;
    const float xi = x[i];
    for (int m = t; m < MD; m += 256) {
        const float2 w = reinterpret_cast<const float2*>(W1)[m];
        sA[m]  = fmaf(xi, w.x, b1[m]);
        sCw[m] = w.y;
    }
    if (t < JT) sxj[t] = x[j0 + t];
    const int tk = t & 15;
    const int tj = t >> 4;
    float w3r[8], b2r[8];
#pragma unroll
    for (int kk = 0; kk < 8; kk++) {
        w3r[kk] = W3[tk * 8 + kk];
        b2r[kk] = b2[tk * 8 + kk];
    }
    float acc[8][8];
#pragma unroll
    for (int jj = 0; jj < 8; jj++)
#pragma unroll
        for (int kk = 0; kk < 8; kk++) acc[jj][kk] = 0.f;
    const int jx   = t & 127;
    const int mseg = (t >> 7) * 16;
    __syncthreads();
    const float xjv = sxj[jx];
    for (int m0 = 0; m0 < MD; m0 += MC) {
#pragma unroll
        for (int q = 0; q < 4; q++) {
            const int f   = t + q * 256;
            const int k   = f >> 3;
            const int mm4 = (f & 7) * 4;
            const float4 w = *reinterpret_cast<const float4*>(W2 + k * MD + m0 + mm4);
            W2t[mm4 + 0][k] = w.x;
            W2t[mm4 + 1][k] = w.y;
            W2t[mm4 + 2][k] = w.z;
            W2t[mm4 + 3][k] = w.w;
        }
#pragma unroll
        for (int q = 0; q < 16; q++) {
            const int ml = mseg + q;
            const float z = fmaf(xjv, sCw[m0 + ml], sA[m0 + ml]);
            S[ml][jx] = 1.0f / (1.0f + __expf(-z));
        }
        __syncthreads();
#pragma unroll 4
        for (int mm = 0; mm < MC; mm++) {
            const float4 s0 = *reinterpret_cast<const float4*>(&S[mm][tj * 8]);
            const float4 s1 = *reinterpret_cast<const float4*>(&S[mm][tj * 8 + 4]);
            const float4 w0 = *reinterpret_cast<const float4*>(&W2t[mm][tk * 8]);
            const float4 w1 = *reinterpret_cast<const float4*>(&W2t[mm][tk * 8 + 4]);
            const float sj[8] = {s0.x, s0.y, s0.z, s0.w, s1.x, s1.y, s1.z, s1.w};
            const float wk[8] = {w0.x, w0.y, w0.z, w0.w, w1.x, w1.y, w1.z, w1.w};
#pragma unroll
            for (int jj = 0; jj < 8; jj++)
#pragma unroll
                for (int kk = 0; kk < 8; kk++)
                    acc[jj][kk] = fmaf(sj[jj], wk[kk], acc[jj][kk]);
        }
        __syncthreads();
    }
    const float b3v = b3[0];
#pragma unroll
    for (int jj = 0; jj < 8; jj++) {
        float v = 0.f;
#pragma unroll
        for (int kk = 0; kk < 8; kk++) {
            const float h = acc[jj][kk] + b2r[kk];
            v = fmaf(w3r[kk], fmaxf(h, 0.f), v);
        }
#pragma unroll
        for (int off = 8; off >= 1; off >>= 1)
            v += __shfl_xor(v, off, 16);
        if (tk == 0) {
            const int j = j0 + tj * 8 + jj;
            if (j >= i) K[i * NN + j] = v + b3v;
        }
    }
}

// ---------------- Kernel 2: C = K^T K (768^3 fp32 GEMM) --------------------
__global__ __launch_bounds__(256) void ktk(const float* __restrict__ K,
                                           float* __restrict__ C)
{
    const int b0 = blockIdx.x * 64;
    const int a0 = blockIdx.y * 64;
    __shared__ float Ka[64][68];
    __shared__ float Kb[64][68];
    const int t  = threadIdx.x;
    const int tb = t & 15;
    const int ta = t >> 4;
    float acc[4][4];
#pragma unroll
    for (int u = 0; u < 4; u++)
#pragma unroll
        for (int v = 0; v < 4; v++) acc[u][v] = 0.f;
    const int kmax = (a0 < b0 ? a0 : b0) + 64;
    for (int k0 = 0; k0 < kmax; k0 += 64) {
#pragma unroll
        for (int q = 0; q < 4; q++) {
            const int f  = t + q * 256;
            const int kk = f >> 4;
            const int c4 = (f & 15) * 4;
            *reinterpret_cast<float4*>(&Ka[kk][c4]) =
                *reinterpret_cast<const float4*>(K + (k0 + kk) * NN + a0 + c4);
            *reinterpret_cast<float4*>(&Kb[kk][c4]) =
                *reinterpret_cast<const float4*>(K + (k0 + kk) * NN + b0 + c4);
        }
        __syncthreads();
#pragma unroll 8
        for (int kk = 0; kk < 64; kk++) {
            const float4 av = *reinterpret_cast<const float4*>(&Ka[kk][ta * 4]);
            const float4 bv = *reinterpret_cast<const float4*>(&Kb[kk][tb * 4]);
            const float a4[4] = {av.x, av.y, av.z, av.w};
            const float b4[4] = {bv.x, bv.y, bv.z, bv.w};
#pragma unroll
            for (int u = 0; u < 4; u++)
#pragma unroll
                for (int v = 0; v < 4; v++)
                    acc[u][v] = fmaf(a4[u], b4[v], acc[u][v]);
        }
        __syncthreads();
    }
#pragma unroll
    for (int u = 0; u < 4; u++) {
        float4 o;
        o.x = acc[u][0]; o.y = acc[u][1]; o.z = acc[u][2]; o.w = acc[u][3];
        *reinterpret_cast<float4*>(C + (a0 + ta * 4 + u) * NN + b0 + tb * 4) = o;
    }
}

extern "C" void kernel_launch(void* const* d_in, const int* in_sizes, int n_in,
                              void* d_out, int out_size, void* d_ws, size_t ws_size,
                              hipStream_t stream)
{
    const float* x  = (const float*)d_in[0];
    const float* W1 = (const float*)d_in[1];
    const float* b1 = (const float*)d_in[2];
    const float* W2 = (const float*)d_in[3];
    const float* b2 = (const float*)d_in[4];
    const float* W3 = (const float*)d_in[5];
    const float* b3 = (const float*)d_in[6];
    float* Kmat = (float*)d_ws;                       // 2,359,296 B
    float* C    = (float*)d_out;

    const size_t kBytes = (size_t)NN * NN * sizeof(float);
    const size_t need   = kBytes + 262144;            // + W2 bf16 swizzled

    hipMemsetAsync(Kmat, 0, kBytes, stream);
    if (ws_size >= need) {
        ushort* WhiS = (ushort*)((char*)d_ws + kBytes);
        w2bf16<<<64, 256, 0, stream>>>(W2, WhiS);
        mlp_pairs<<<NPBLK2, 256, 0, stream>>>(x, W1, b1, WhiS, b2, W3, b3, Kmat);
    } else {
        mlp_fill<<<dim3(6, NN), 256, 0, stream>>>(x, W1, b1, W2, b2, W3, b3, Kmat);
    }
    ktk<<<dim3(NN / 64, NN / 64), 256, 0, stream>>>(Kmat, C);
}